// Round 13
// baseline (409.283 us; speedup 1.0000x reference)
//
#include <hip/hip_runtime.h>

#define NN 2048
#define GG 64
#define TS 128
#define NT (NN / TS)                 // 16 tiles
#define NPAIR (NT * (NT + 1) / 2)    // 136 tile pairs
#define MAXE 14336
#define EBUF 3072
#define STH 512
// amplification factors (diagnostic round): phase cost = (kernel_dur - init) / AMP
#define AMP_PREP 16
#define AMP_PAIR 8
#define AMP_CSR  8
#define AMP_FIXP 8
#define AMP_ATTR 8

typedef unsigned long long u64;
typedef unsigned short u16;
typedef unsigned int u32;

__device__ __forceinline__ float iou4(float4 a, float4 b) {
    float w = fminf(a.z, b.z) - fmaxf(a.x, b.x) + 1.0f;
    float h = fminf(a.w, b.w) - fmaxf(a.y, b.y) + 1.0f;
    w = fmaxf(w, 0.0f);
    h = fmaxf(h, 0.0f);
    float ov = w * h;
    float aa = (a.z - a.x + 1.0f) * (a.w - a.y + 1.0f);
    float ab = (b.z - b.x + 1.0f) * (b.w - b.y + 1.0f);
    return ov / (aa + ab - ov);
}

__device__ __forceinline__ float wredf(float v) {
    for (int o = 32; o > 0; o >>= 1) v += __shfl_down(v, o);
    return v;
}
__device__ __forceinline__ int wredi(int v) {
    for (int o = 32; o > 0; o >>= 1) v += __shfl_down(v, o);
    return v;
}

__device__ __forceinline__ bool earlier(u32 sa, int a, u32 sb, int b) {
    return (sa > sb) || (sa == sb && a < b);
}
__device__ __forceinline__ u64 make_key(u32 sbits, int j) {
    return ((u64)sbits << 32) | (u64)(NN - 1 - j);
}

// ---------------- P0: transpose proposals to SoA ----------------
__global__ __launch_bounds__(STH) void prep_amp(const int* __restrict__ gt_inds,
                                                const float* __restrict__ props,
                                                float4* __restrict__ sbox, float* __restrict__ ssc,
                                                int* __restrict__ sgt) {
    __shared__ float pbL[NN * 5];
    const int im = blockIdx.x, tid = threadIdx.x;
    const float4* pv = (const float4*)(props + (size_t)im * NN * 5);
    float4* pl4 = (float4*)pbL;
    const int base = im * NN;
    const int* gbi = gt_inds + (size_t)im * NN;
    for (int it = 0; it < AMP_PREP; ++it) {
        for (int x = tid; x < NN * 5 / 4; x += STH) pl4[x] = pv[x];
        __syncthreads();
        for (int j = tid; j < NN; j += STH) {
            sbox[base + j] = make_float4(pbL[j * 5], pbL[j * 5 + 1], pbL[j * 5 + 2], pbL[j * 5 + 3]);
            ssc[base + j] = pbL[j * 5 + 4];
            sgt[base + j] = gbi[j];
        }
        __syncthreads();
    }
}

// ---------------- P1: pair phase -> edge list ----------------
__global__ __launch_bounds__(256) void pair_amp(const float4* __restrict__ sbox,
                                                const float* __restrict__ ssc,
                                                const int* __restrict__ sgt,
                                                int* __restrict__ ecnt, u32* __restrict__ edges) {
    const int im = blockIdx.x / NPAIR;
    int q = blockIdx.x % NPAIR;
    int ta = 0;
    while (q >= NT - ta) { q -= NT - ta; ++ta; }
    const int tb = ta + q;
    const int base = im * NN;

    __shared__ float4 Abox[TS], Bbox[TS];
    __shared__ u32 Asc[TS], Bsc[TS];
    __shared__ int Ag[TS], Bg[TS];
    __shared__ u32 ebuf[EBUF];
    __shared__ int lcnt, gbase;
    const int tid = threadIdx.x;
    int* ec = ecnt + im * 32;
    u32* ge = edges + (size_t)im * MAXE;

    for (int it = 0; it < AMP_PAIR; ++it) {
        if (tid == 0) lcnt = 0;
        __syncthreads();
        for (int t = tid; t < TS; t += 256) {
            Abox[t] = sbox[base + ta * TS + t];
            Asc[t] = __float_as_uint(ssc[base + ta * TS + t]);
            Ag[t] = sgt[base + ta * TS + t];
            Bbox[t] = sbox[base + tb * TS + t];
            Bsc[t] = __float_as_uint(ssc[base + tb * TS + t]);
            Bg[t] = sgt[base + tb * TS + t];
        }
        __syncthreads();
        const int pr = tid & (TS - 1);
        const int half = tid >> 7;
        const float4 rb = Abox[pr];
        const u32 rs = Asc[pr];
        const int i = ta * TS + pr;
        if (Ag[pr] >= 0) {
            #pragma unroll 4
            for (int k = 0; k < TS / 2; ++k) {
                int jl = half * (TS / 2) + k;
                if (ta == tb && jl <= pr) continue;
                if (Bg[jl] < 0) continue;
                float v = iou4(rb, Bbox[jl]);
                if (v > 0.5f) {
                    int j = tb * TS + jl;
                    int late, early;
                    if (earlier(rs, i, Bsc[jl], j)) { late = j; early = i; }
                    else                            { late = i; early = j; }
                    u32 packed = ((u32)late << 16) | (u32)early;
                    int slot = atomicAdd(&lcnt, 1);
                    if (slot < EBUF) ebuf[slot] = packed;
                    else if (it == AMP_PAIR - 1) {          // spill counted exactly once
                        int gs = atomicAdd(ec, 1);
                        if (gs < MAXE) ge[gs] = packed;
                    }
                }
            }
        }
        __syncthreads();
    }
    const int n = min(lcnt, EBUF);
    if (tid == 0) gbase = (n > 0) ? atomicAdd(ec, n) : 0;
    __syncthreads();
    for (int e = tid; e < n; e += 256) {
        int gidx = gbase + e;
        if (gidx < MAXE) ge[gidx] = ebuf[e];
    }
}

// ---------------- P2: CSR build from edge list ----------------
__global__ __launch_bounds__(STH) void csr_amp(const int* __restrict__ ecnt, const u32* __restrict__ edges,
                                               u16* __restrict__ eoff_g, u16* __restrict__ ent_g) {
    __shared__ int cw[NN];
    __shared__ u16 eoff[NN + 2];
    __shared__ u16 ent[MAXE];
    __shared__ int wtot[STH / 64];
    const int im = blockIdx.x, tid = threadIdx.x;
    const int lane = tid & 63, wid = tid >> 6;
    const u32* ge = edges + (size_t)im * MAXE;
    const int E = min(ecnt[im * 32], MAXE);
    if (tid == 0) eoff[NN + 1] = 0;

    for (int it = 0; it < AMP_CSR; ++it) {
        for (int j = tid; j < NN; j += STH) cw[j] = 0;
        __syncthreads();
        for (int e = tid; e < E; e += STH) atomicAdd(&cw[ge[e] >> 16], 1);
        __syncthreads();
        {
            int j0 = tid * 4;
            int c0 = cw[j0], c1 = cw[j0 + 1], c2 = cw[j0 + 2], c3 = cw[j0 + 3];
            int s = c0 + c1 + c2 + c3;
            int incl = s;
            for (int o = 1; o < 64; o <<= 1) {
                int v = __shfl_up(incl, o);
                if (lane >= o) incl += v;
            }
            if (lane == 63) wtot[wid] = incl;
            __syncthreads();
            int wpre = 0;
            for (int wq = 0; wq < wid; ++wq) wpre += wtot[wq];
            int excl = wpre + incl - s;
            eoff[j0] = (u16)excl;
            eoff[j0 + 1] = (u16)(excl + c0);
            eoff[j0 + 2] = (u16)(excl + c0 + c1);
            eoff[j0 + 3] = (u16)(excl + c0 + c1 + c2);
            if (tid == STH - 1) eoff[NN] = (u16)(excl + s);
            cw[j0] = excl;
            cw[j0 + 1] = excl + c0;
            cw[j0 + 2] = excl + c0 + c1;
            cw[j0 + 3] = excl + c0 + c1 + c2;
        }
        __syncthreads();
        for (int e = tid; e < E; e += STH) {
            u32 x = ge[e];
            int pos = atomicAdd(&cw[x >> 16], 1);
            ent[pos] = (u16)(x & 0xffffu);
        }
        __syncthreads();
    }
    u32* eg = (u32*)(eoff_g + (size_t)im * (NN + 2));
    for (int x = tid; x < (NN + 2) / 2; x += STH) eg[x] = ((u32*)eoff)[x];
    u32* ng = (u32*)(ent_g + (size_t)im * MAXE);
    for (int x = tid; x < (E + 1) / 2; x += STH) ng[x] = ((u32*)ent)[x];
}

// ---------------- P3: worklist fixpoint ----------------
__global__ __launch_bounds__(STH) void fixp_amp(const int* __restrict__ sgt,
                                                const int* __restrict__ ecnt,
                                                const u16* __restrict__ eoff_g, const u16* __restrict__ ent_g,
                                                unsigned char* __restrict__ st_g) {
    __shared__ u16 wl[2][NN];
    __shared__ u16 eoff[NN + 2];
    __shared__ u16 ent[MAXE];
    __shared__ unsigned char st[NN];
    __shared__ signed char gpos[NN];
    __shared__ int s_cnt[2];
    const int im = blockIdx.x, tid = threadIdx.x;
    const u16* eg16 = eoff_g + (size_t)im * (NN + 2);
    const int E = min(ecnt[im * 32], MAXE);
    volatile unsigned char* vst = st;

    for (int x = tid; x < (NN + 2) / 2; x += STH) ((u32*)eoff)[x] = ((const u32*)eg16)[x];
    const u32* ng = (const u32*)(ent_g + (size_t)im * MAXE);
    for (int x = tid; x < (E + 1) / 2; x += STH) ((u32*)ent)[x] = ng[x];
    for (int j = tid; j < NN; j += STH) gpos[j] = (sgt[im * NN + j] >= 0) ? 0 : 2;
    __syncthreads();

    for (int it = 0; it < AMP_FIXP; ++it) {
        if (tid == 0) { s_cnt[0] = 0; s_cnt[1] = 0; }
        for (int j = tid; j < NN; j += STH) st[j] = (unsigned char)gpos[j];
        __syncthreads();
        // round 1: full sweep + compact
        for (int j = tid; j < NN; j += STH) {
            if (st[j] != 0) continue;
            int e0 = eoff[j], e1 = eoff[j + 1];
            bool anyK = false, anyU = false;
            for (int e = e0; e < e1; ++e) {
                unsigned char s = vst[ent[e]];
                anyK |= (s == 1);
                anyU |= (s == 0);
            }
            if (anyK) st[j] = 2;
            else if (!anyU) st[j] = 1;
            else { int pos = atomicAdd(&s_cnt[0], 1); wl[0][pos] = (u16)j; }
        }
        __syncthreads();
        int src = 0;
        int nwl = s_cnt[0];
        while (nwl > 0) {
            #pragma unroll
            for (int r = 0; r < 2; ++r) {
                for (int w = tid; w < nwl; w += STH) {
                    int j = wl[src][w];
                    if (st[j] != 0) continue;
                    int e0 = eoff[j], e1 = eoff[j + 1];
                    bool anyK = false, anyU = false;
                    for (int e = e0; e < e1; ++e) {
                        unsigned char s = vst[ent[e]];
                        anyK |= (s == 1);
                        anyU |= (s == 0);
                    }
                    if (anyK) st[j] = 2;
                    else if (!anyU) st[j] = 1;
                }
            }
            for (int w = tid; w < nwl; w += STH) {
                int j = wl[src][w];
                if (st[j] != 0) continue;
                int e0 = eoff[j], e1 = eoff[j + 1];
                bool anyK = false, anyU = false;
                for (int e = e0; e < e1; ++e) {
                    unsigned char s = vst[ent[e]];
                    anyK |= (s == 1);
                    anyU |= (s == 0);
                }
                if (anyK) st[j] = 2;
                else if (!anyU) st[j] = 1;
                else { int pos = atomicAdd(&s_cnt[src ^ 1], 1); wl[src ^ 1][pos] = (u16)j; }
            }
            __syncthreads();
            nwl = s_cnt[src ^ 1];
            if (tid == 0) s_cnt[src] = 0;
            src ^= 1;
            __syncthreads();
        }
    }
    u32* stg = (u32*)(st_g + (size_t)im * NN);
    for (int x = tid; x < NN / 4; x += STH) stg[x] = ((u32*)st)[x];
}

// ---------------- P4: attribution + accumulation + finalize ----------------
__global__ __launch_bounds__(STH) void attr_amp(const int* __restrict__ sgt_g,
                                                const float* __restrict__ gt_boxes,
                                                const float4* __restrict__ sbox,
                                                const float* __restrict__ ssc,
                                                const int* __restrict__ ecnt,
                                                const unsigned char* __restrict__ st_g,
                                                const u16* __restrict__ eoff_g, const u16* __restrict__ ent_g,
                                                float* __restrict__ acc, u32* __restrict__ ctr2,
                                                float* __restrict__ out, int B) {
    __shared__ u32 scoreL[NN];
    __shared__ float sumA[NN];
    __shared__ u32 cntA[NN];
    __shared__ u16 eoff[NN + 2];
    __shared__ u16 ent[MAXE];
    __shared__ unsigned char st[NN];
    __shared__ signed char gtL[NN];
    __shared__ u32 hkw[NN / 32];
    __shared__ float4 gtb[GG];
    __shared__ u64 firstk[GG];
    __shared__ u64 s_minkey;
    __shared__ int s_pos, s_qcnt, s_pcnt;
    __shared__ float s_tpush, s_tpull;

    const int im = blockIdx.x, tid = threadIdx.x;
    const int lane = tid & 63;
    const int base = im * NN;

    // one-time imports
    if (tid < GG) gtb[tid] = ((const float4*)(gt_boxes + (size_t)im * GG * 4))[tid];
    const int E = min(ecnt[im * 32], MAXE);
    const u32* stg = (const u32*)(st_g + (size_t)im * NN);
    for (int x = tid; x < NN / 4; x += STH) ((u32*)st)[x] = stg[x];
    const u32* eg = (const u32*)(eoff_g + (size_t)im * (NN + 2));
    for (int x = tid; x < (NN + 2) / 2; x += STH) ((u32*)eoff)[x] = eg[x];
    const u32* ng = (const u32*)(ent_g + (size_t)im * MAXE);
    for (int x = tid; x < (E + 1) / 2; x += STH) ((u32*)ent)[x] = ng[x];
    for (int j = tid; j < NN; j += STH) {
        scoreL[j] = __float_as_uint(ssc[base + j]);
        int g = sgt_g[base + j];
        gtL[j] = (signed char)((g < 0) ? -1 : g);
    }
    __syncthreads();

    for (int it = 0; it < AMP_ATTR; ++it) {
        // per-iter reset
        if (tid == 0) { s_pos = 0; s_qcnt = 0; s_pcnt = 0; s_tpush = 0.f; s_tpull = 0.f; s_minkey = ~0ull; }
        if (tid < GG) firstk[tid] = 0ull;
        if (tid < NN / 32) hkw[tid] = 0u;
        int lpos = 0;
        for (int j = tid; j < NN; j += STH) {
            sumA[j] = 0.f; cntA[j] = 0;
            lpos += (gtL[j] >= 0) ? 1 : 0;
        }
        lpos = wredi(lpos);
        if (lane == 0 && lpos) atomicAdd(&s_pos, lpos);
        __syncthreads();

        // pass 1
        for (int j = tid; j < NN; j += STH) {
            int g = gtL[j];
            if (st[j] == 1) {
                u64 kj = make_key(scoreL[j], j);
                atomicMin(&s_minkey, kj);
                atomicMax(&firstk[g], kj);
            } else if (g >= 0) {
                int e0 = eoff[j], e1 = eoff[j + 1];
                int ki = -1; u32 ks = 0;
                for (int e = e0; e < e1; ++e) {
                    int ii = ent[e];
                    if (st[ii] == 1 && (ki < 0 || earlier(scoreL[ii], ii, ks, ki))) { ki = ii; ks = scoreL[ii]; }
                }
                if (ki < 0) continue;
                atomicOr(&hkw[ki >> 5], 1u << (ki & 31));
                float v = iou4(sbox[base + ki], sbox[base + j]);
                int gi = gtL[ki];
                if (g != gi && v > iou4(gtb[gi], gtb[g])) {
                    atomicAdd(&cntA[ki], 1u);
                    atomicAdd(&sumA[ki], -logf(1.5f - v) * __uint_as_float(scoreL[j]));
                }
            }
        }
        __syncthreads();

        // pass 2
        float ltpush = 0.f, ltpull = 0.f;
        int lqcnt = 0, lpcnt = 0;
        const u64 minkey = s_minkey;
        for (int i = tid; i < NN; i += STH) {
            if (st[i] != 1) continue;
            int g = gtL[i];
            u64 ky = make_key(scoreL[i], i);
            u64 fk = firstk[g];
            bool hkb = (hkw[i >> 5] >> (i & 31)) & 1u;
            bool add = (ky != minkey) || hkb;
            int c = (int)cntA[i];
            bool hr = fk > ky;
            if (add && c > 0) ltpush += sumA[i] / (float)c;
            if (add) lqcnt += c;
            if (hr) ++lpcnt;
            if (add && hr) {
                int r = (NN - 1) - (int)(fk & 0xffffffffu);
                float v = iou4(sbox[base + i], sbox[base + r]);
                ltpull += -logf(fmaxf(v, 1e-6f)) * __uint_as_float(scoreL[i]);
            }
        }
        ltpush = wredf(ltpush); ltpull = wredf(ltpull);
        lqcnt = wredi(lqcnt); lpcnt = wredi(lpcnt);
        if (lane == 0) {
            if (ltpush != 0.f) atomicAdd(&s_tpush, ltpush);
            if (ltpull != 0.f) atomicAdd(&s_tpull, ltpull);
            if (lqcnt) atomicAdd(&s_qcnt, lqcnt);
            if (lpcnt) atomicAdd(&s_pcnt, lpcnt);
        }
        __syncthreads();
    }

    // finalize from the last iteration's (identical) results
    if (tid == 0) {
        float valid = (s_pos > 1) ? 1.0f : 0.0f;
        float push_b = s_tpush / ((float)s_qcnt + 1e-6f) * valid;
        float pull_b = s_tpull / ((float)s_pcnt + 1e-6f) * valid;
        atomicAdd(&acc[0], push_b);
        atomicAdd(&acc[1], pull_b);
        __threadfence();
        u32 old = atomicAdd(ctr2, 1u);
        if (old == (u32)(B - 1)) {
            float ps = atomicAdd(&acc[0], 0.0f);
            float pl = atomicAdd(&acc[1], 0.0f);
            float inv = 1.0f / (float)B;
            out[0] = ps * inv * 1.0f;  // push_loss * PUSH_W
            out[1] = pl * inv * 1.0f;  // pull_loss * PULL_W
        }
    }
}

extern "C" void kernel_launch(void* const* d_in, const int* in_sizes, int n_in,
                              void* d_out, int out_size, void* d_ws, size_t ws_size,
                              hipStream_t stream) {
    const int B = in_sizes[0] / NN;
    const int* anchor_gt = (const int*)d_in[1];
    const float* gtb = (const float*)d_in[2];
    const float* props = (const float*)d_in[3];

    char* w = (char*)d_ws;
    int* ecnt = (int*)w;                                  // B × 128 B
    float* acc = (float*)(w + (size_t)B * 128);
    u32* ctr2 = (u32*)(w + (size_t)B * 128 + 8);
    size_t o = (size_t)B * 128 + 128;
    float4* sbox = (float4*)(w + o);        o += (size_t)B * NN * 16;
    float* ssc = (float*)(w + o);           o += (size_t)B * NN * 4;
    int* sgt = (int*)(w + o);               o += (size_t)B * NN * 4;
    u32* edges = (u32*)(w + o);             o += (size_t)B * MAXE * 4;
    unsigned char* st_g = (unsigned char*)(w + o); o += (size_t)B * NN;
    u16* eoff_g = (u16*)(w + o);            o += (size_t)B * (NN + 2) * 2;
    u16* ent_g = (u16*)(w + o);

    hipMemsetAsync(d_ws, 0, (size_t)B * 128 + 128, stream);
    prep_amp<<<dim3(B), dim3(STH), 0, stream>>>(anchor_gt, props, sbox, ssc, sgt);
    pair_amp<<<dim3(B * NPAIR), dim3(256), 0, stream>>>(sbox, ssc, sgt, ecnt, edges);
    csr_amp<<<dim3(B), dim3(STH), 0, stream>>>(ecnt, edges, eoff_g, ent_g);
    fixp_amp<<<dim3(B), dim3(STH), 0, stream>>>(sgt, ecnt, eoff_g, ent_g, st_g);
    attr_amp<<<dim3(B), dim3(STH), 0, stream>>>(sgt, gtb, sbox, ssc, ecnt, st_g, eoff_g, ent_g,
                                                acc, ctr2, (float*)d_out, B);
}

// Round 14
// 54.927 us; speedup vs baseline: 7.4513x; 7.4513x over previous
//
#include <hip/hip_runtime.h>

#define NN 2048
#define GG 64
#define TS 128
#define NT (NN / TS)                 // 16 tiles
#define NPAIR (NT * (NT + 1) / 2)    // 136 tile pairs
#define MAXE 14336                   // per-image edge cap (est. E ~ 3000)
#define EBUF 3072                    // per-block LDS edge buffer
#define STH 512                      // scan threads

typedef unsigned long long u64;
typedef unsigned short u16;
typedef unsigned int u32;

__device__ __forceinline__ float iou4(float4 a, float4 b) {
    float w = fminf(a.z, b.z) - fmaxf(a.x, b.x) + 1.0f;
    float h = fminf(a.w, b.w) - fmaxf(a.y, b.y) + 1.0f;
    w = fmaxf(w, 0.0f);
    h = fmaxf(h, 0.0f);
    float ov = w * h;
    float aa = (a.z - a.x + 1.0f) * (a.w - a.y + 1.0f);
    float ab = (b.z - b.x + 1.0f) * (b.w - b.y + 1.0f);
    return ov / (aa + ab - ov);
}

__device__ __forceinline__ float wredf(float v) {
    for (int o = 32; o > 0; o >>= 1) v += __shfl_down(v, o);
    return v;
}
__device__ __forceinline__ int wredi(int v) {
    for (int o = 32; o > 0; o >>= 1) v += __shfl_down(v, o);
    return v;
}
__device__ __forceinline__ u64 wredmin64(u64 v) {
    for (int o = 32; o > 0; o >>= 1) {
        u64 w = __shfl_down(v, o);
        v = (w < v) ? w : v;
    }
    return v;
}

// selection order: earlier = higher score, tie -> lower original index (scores >= 0).
__device__ __forceinline__ bool earlier(u32 sa, int a, u32 sb, int b) {
    return (sa > sb) || (sa == sb && a < b);
}
__device__ __forceinline__ u64 make_key(u32 sbits, int j) {
    return ((u64)sbits << 32) | (u64)(NN - 1 - j);
}
__device__ __forceinline__ float4 load_box(const float* pb, int j) {
    return make_float4(pb[j * 5 + 0], pb[j * 5 + 1], pb[j * 5 + 2], pb[j * 5 + 3]);
}

// ---------------- K1: balanced LDS-tiled pair phase -> compact edge list ----------------
__global__ __launch_bounds__(256) void pair_kernel(const int* __restrict__ gt_inds,
                                                   const float* __restrict__ props,
                                                   int* __restrict__ ecnt, u32* __restrict__ edges) {
    const int im = blockIdx.x / NPAIR;
    int q = blockIdx.x % NPAIR;
    int ta = 0;
    while (q >= NT - ta) { q -= NT - ta; ++ta; }
    const int tb = ta + q;
    const float* pb = props + (size_t)im * NN * 5;
    const int* gbi = gt_inds + (size_t)im * NN;

    __shared__ float4 Abox[TS], Bbox[TS];
    __shared__ u32 Asc[TS], Bsc[TS];
    __shared__ int Ag[TS], Bg[TS];
    __shared__ u32 ebuf[EBUF];
    __shared__ int lcnt, gbase;
    const int tid = threadIdx.x;
    if (tid == 0) lcnt = 0;

    for (int t = tid; t < 2 * TS; t += 256) {
        int half = t >> 7, r = t & (TS - 1);
        int j = (half ? tb : ta) * TS + r;
        float4 bx = load_box(pb, j);
        u32 sb = __float_as_uint(pb[j * 5 + 4]);
        int g = gbi[j];
        if (half == 0) { Abox[r] = bx; Asc[r] = sb; Ag[r] = g; }
        else           { Bbox[r] = bx; Bsc[r] = sb; Bg[r] = g; }
    }
    __syncthreads();

    const int pr = tid & (TS - 1);      // row in tile A
    const int half = tid >> 7;          // column half in tile B
    const float4 rb = Abox[pr];
    const u32 rs = Asc[pr];
    const int i = ta * TS + pr;
    int* ec = ecnt + im * 32;           // 128B-padded per-image counter
    u32* ge = edges + (size_t)im * MAXE;
    if (Ag[pr] >= 0) {
        #pragma unroll 4
        for (int k = 0; k < TS / 2; ++k) {
            int jl = half * (TS / 2) + k;
            if (ta == tb && jl <= pr) continue;   // each unordered pair once
            if (Bg[jl] < 0) continue;
            float v = iou4(rb, Bbox[jl]);
            if (v > 0.5f) {
                int j = tb * TS + jl;
                int late, early;
                if (earlier(rs, i, Bsc[jl], j)) { late = j; early = i; }
                else                            { late = i; early = j; }
                u32 packed = ((u32)late << 16) | (u32)early;
                int slot = atomicAdd(&lcnt, 1);            // LDS atomic
                if (slot < EBUF) ebuf[slot] = packed;
                else {                                      // spill (essentially never)
                    int gs = atomicAdd(ec, 1);
                    if (gs < MAXE) ge[gs] = packed;
                }
            }
        }
    }
    __syncthreads();
    const int n = min(lcnt, EBUF);
    if (tid == 0) gbase = (n > 0) ? atomicAdd(ec, n) : 0;   // one global atomic per block
    __syncthreads();
    for (int e = tid; e < n; e += 256) {
        int gidx = gbase + e;
        if (gidx < MAXE) ge[gidx] = ebuf[e];                // coalesced copy
    }
}

// ---------------- K2: LDS CSR + worklist fixpoint + attribution + fused finalize ----------------
union SumWl {
    float sumA[NN];                   // 8 KB (pass 1/2 only)
    u16 wl[2][NN];                    // fixpoint worklists
};

__global__ __launch_bounds__(STH) void scan_kernel(const int* __restrict__ gt_inds,
                                                   const float* __restrict__ gt_boxes,
                                                   const float* __restrict__ props,
                                                   const int* __restrict__ ecnt, const u32* __restrict__ edges,
                                                   float* __restrict__ acc, u32* __restrict__ ctr2,
                                                   float* __restrict__ out, int B) {
    __shared__ u32 scoreL[NN];            // 8 KB (float bits)
    __shared__ SumWl u;                   // 8 KB
    __shared__ int cw[NN];                // 8 KB: count -> cursor -> cntA
    __shared__ u16 eoff[NN + 1];          // 4 KB
    __shared__ u16 ent[MAXE];             // 28 KB
    __shared__ unsigned char st[NN];      // 0=unresolved 1=kept 2=killed
    __shared__ unsigned char hk[NN];
    __shared__ float4 gtb[GG];            // 1 KB
    __shared__ u64 firstk[GG];            // max key among kept per gt (0 = none)
    __shared__ int wtot[STH / 64];
    __shared__ int s_cnt[2];              // parity worklist counters
    __shared__ u64 s_minkey;
    __shared__ int s_pos, s_qcnt, s_pcnt;
    __shared__ float s_tpush, s_tpull;

    const int im = blockIdx.x, tid = threadIdx.x;
    const int lane = tid & 63, wid = tid >> 6;
    const float* pb = props + (size_t)im * NN * 5;
    const int* gbi = gt_inds + (size_t)im * NN;
    const u32* ge = edges + (size_t)im * MAXE;
    volatile unsigned char* vst = st;     // fixpoint reads must not be register-cached

    if (tid == 0) {
        s_pos = 0; s_qcnt = 0; s_pcnt = 0; s_tpush = 0.f; s_tpull = 0.f; s_minkey = ~0ull;
        s_cnt[0] = 0; s_cnt[1] = 0;
    }
    if (tid < GG) {
        firstk[tid] = 0ull;
        const float* gt = gt_boxes + (size_t)im * GG * 4;
        gtb[tid] = make_float4(gt[tid * 4 + 0], gt[tid * 4 + 1], gt[tid * 4 + 2], gt[tid * 4 + 3]);
    }
    int lpos = 0;
    for (int j = tid; j < NN; j += STH) {
        int g = gbi[j];
        st[j] = (g >= 0) ? 0 : 2;
        lpos += (g >= 0) ? 1 : 0;
        scoreL[j] = __float_as_uint(pb[j * 5 + 4]);
        cw[j] = 0; hk[j] = 0;
    }
    lpos = wredi(lpos);
    if (lane == 0 && lpos) atomicAdd(&s_pos, lpos);
    __syncthreads();

    // ---- build LDS CSR from the edge list ----
    const int E = min(ecnt[im * 32], MAXE);
    for (int e = tid; e < E; e += STH) atomicAdd(&cw[ge[e] >> 16], 1);
    __syncthreads();
    {   // block-wide exclusive prefix sum over 2048 counts (4 per thread)
        int j0 = tid * 4;
        int c0 = cw[j0], c1 = cw[j0 + 1], c2 = cw[j0 + 2], c3 = cw[j0 + 3];
        int s = c0 + c1 + c2 + c3;
        int incl = s;
        for (int o = 1; o < 64; o <<= 1) {
            int v = __shfl_up(incl, o);
            if (lane >= o) incl += v;
        }
        if (lane == 63) wtot[wid] = incl;
        __syncthreads();
        int wpre = 0;
        for (int wq = 0; wq < wid; ++wq) wpre += wtot[wq];
        int excl = wpre + incl - s;
        eoff[j0] = (u16)excl;
        eoff[j0 + 1] = (u16)(excl + c0);
        eoff[j0 + 2] = (u16)(excl + c0 + c1);
        eoff[j0 + 3] = (u16)(excl + c0 + c1 + c2);
        if (tid == STH - 1) eoff[NN] = (u16)(excl + s);
        cw[j0] = excl;
        cw[j0 + 1] = excl + c0;
        cw[j0 + 2] = excl + c0 + c1;
        cw[j0 + 3] = excl + c0 + c1 + c2;
    }
    __syncthreads();
    for (int e = tid; e < E; e += STH) {
        u32 x = ge[e];
        int pos = atomicAdd(&cw[x >> 16], 1);
        ent[pos] = (u16)(x & 0xffffu);
    }
    __syncthreads();

    // ---- fixpoint round 1: full sweep, compact unresolved into worklist 0 ----
    for (int j = tid; j < NN; j += STH) {
        if (st[j] != 0) continue;
        int e0 = eoff[j], e1 = eoff[j + 1];
        bool anyK = false, anyU = false;
        for (int e = e0; e < e1; ++e) {
            unsigned char s = vst[ent[e]];
            anyK |= (s == 1);
            anyU |= (s == 0);
        }
        if (anyK) st[j] = 2;
        else if (!anyU) st[j] = 1;
        else { int pos = atomicAdd(&s_cnt[0], 1); u.wl[0][pos] = (u16)j; }
    }
    __syncthreads();

    // ---- fixpoint rounds: worklist only, 3 relaxation sub-sweeps per barrier ----
    int src = 0;
    int nwl = s_cnt[0];
    while (nwl > 0) {
        #pragma unroll
        for (int r = 0; r < 2; ++r) {       // benign-race relaxations (monotone st)
            for (int w = tid; w < nwl; w += STH) {
                int j = u.wl[src][w];
                if (st[j] != 0) continue;
                int e0 = eoff[j], e1 = eoff[j + 1];
                bool anyK = false, anyU = false;
                for (int e = e0; e < e1; ++e) {
                    unsigned char s = vst[ent[e]];
                    anyK |= (s == 1);
                    anyU |= (s == 0);
                }
                if (anyK) st[j] = 2;
                else if (!anyU) st[j] = 1;
            }
        }
        for (int w = tid; w < nwl; w += STH) {
            int j = u.wl[src][w];
            if (st[j] != 0) continue;
            int e0 = eoff[j], e1 = eoff[j + 1];
            bool anyK = false, anyU = false;
            for (int e = e0; e < e1; ++e) {
                unsigned char s = vst[ent[e]];
                anyK |= (s == 1);
                anyU |= (s == 0);
            }
            if (anyK) st[j] = 2;
            else if (!anyU) st[j] = 1;
            else { int pos = atomicAdd(&s_cnt[src ^ 1], 1); u.wl[src ^ 1][pos] = (u16)j; }
        }
        __syncthreads();
        nwl = s_cnt[src ^ 1];
        if (tid == 0) s_cnt[src] = 0;
        src ^= 1;
        __syncthreads();
    }

    // ---- worklists dead; zero sumA and cw (cntA) ----
    for (int j = tid; j < NN; j += STH) { u.sumA[j] = 0.f; cw[j] = 0; }
    __syncthreads();

    // ---- pass 1a: kept bookkeeping — minkey via wave reduction (NOT per-thread atomics) ----
    u64 lmin = ~0ull;
    for (int j = tid; j < NN; j += STH) {
        if (st[j] != 1) continue;
        u64 kj = make_key(scoreL[j], j);
        if (kj < lmin) lmin = kj;
        atomicMax(&firstk[gbi[j]], kj);      // 64 distinct LDS addresses: tolerable
    }
    lmin = wredmin64(lmin);
    if (lane == 0 && lmin != ~0ull) atomicMin(&s_minkey, lmin);   // 8 atomics total

    // ---- pass 1b: killer attribution (killed positives only) ----
    for (int j = tid; j < NN; j += STH) {
        int g = gbi[j];
        if (st[j] != 2 || g < 0) continue;
        int e0 = eoff[j], e1 = eoff[j + 1];
        int ki = -1; u32 ks = 0;
        for (int e = e0; e < e1; ++e) {
            int ii = ent[e];
            if (st[ii] == 1 && (ki < 0 || earlier(scoreL[ii], ii, ks, ki))) { ki = ii; ks = scoreL[ii]; }
        }
        if (ki < 0) continue;             // cannot happen for a killed positive
        hk[ki] = 1;                       // benign race: all write 1
        float v = iou4(load_box(pb, ki), load_box(pb, j));
        int gi = gbi[ki];
        if (g != gi && v > iou4(gtb[gi], gtb[g])) {
            atomicAdd(&cw[ki], 1);
            atomicAdd(&u.sumA[ki], -logf(1.5f - v) * pb[j * 5 + 4]);
        }
    }
    __syncthreads();

    // ---- pass 2: accumulation over kept selections (order-free) ----
    float ltpush = 0.f, ltpull = 0.f;
    int lqcnt = 0, lpcnt = 0;
    const u64 minkey = s_minkey;
    for (int i = tid; i < NN; i += STH) {
        if (st[i] != 1) continue;
        int g = gbi[i];
        u64 ky = make_key(scoreL[i], i);
        u64 fk = firstk[g];
        bool add = (ky != minkey) || (hk[i] != 0);   // any(alive_p) at this selection
        int c = cw[i];
        bool hr = fk > ky;                            // earlier kept with same gt
        if (add && c > 0) ltpush += u.sumA[i] / (float)c;
        if (add) lqcnt += c;
        if (hr) ++lpcnt;                              // counted even when !add (matches ref)
        if (add && hr) {
            int r = (NN - 1) - (int)(fk & 0xffffffffu);
            float v = iou4(load_box(pb, i), load_box(pb, r));
            ltpull += -logf(fmaxf(v, 1e-6f)) * pb[i * 5 + 4];
        }
    }
    ltpush = wredf(ltpush); ltpull = wredf(ltpull);
    lqcnt = wredi(lqcnt); lpcnt = wredi(lpcnt);
    if (lane == 0) {
        if (ltpush != 0.f) atomicAdd(&s_tpush, ltpush);
        if (ltpull != 0.f) atomicAdd(&s_tpull, ltpull);
        if (lqcnt) atomicAdd(&s_qcnt, lqcnt);
        if (lpcnt) atomicAdd(&s_pcnt, lpcnt);
    }
    __syncthreads();

    // ---- cross-image finalize: last-finishing block writes the B-mean ----
    if (tid == 0) {
        float valid = (s_pos > 1) ? 1.0f : 0.0f;
        float push_b = s_tpush / ((float)s_qcnt + 1e-6f) * valid;
        float pull_b = s_tpull / ((float)s_pcnt + 1e-6f) * valid;
        atomicAdd(&acc[0], push_b);
        atomicAdd(&acc[1], pull_b);
        __threadfence();
        u32 old = atomicAdd(ctr2, 1u);
        if (old == (u32)(B - 1)) {
            float ps = atomicAdd(&acc[0], 0.0f);   // coherent device-scope read
            float pl = atomicAdd(&acc[1], 0.0f);
            float inv = 1.0f / (float)B;
            out[0] = ps * inv * 1.0f;  // push_loss * PUSH_W
            out[1] = pl * inv * 1.0f;  // pull_loss * PULL_W
        }
    }
}

extern "C" void kernel_launch(void* const* d_in, const int* in_sizes, int n_in,
                              void* d_out, int out_size, void* d_ws, size_t ws_size,
                              hipStream_t stream) {
    // inputs: 0=gt_inds(B*N i32), 1=anchor_gt_inds(B*N i32),
    //         2=gt_bboxes(B*G*4 f32), 3=proposal_list(B*N*5 f32)
    const int B = in_sizes[0] / NN;
    const int* anchor_gt = (const int*)d_in[1];
    const float* gtb = (const float*)d_in[2];
    const float* props = (const float*)d_in[3];

    // ---- workspace: [ecnt B*128B | acc 2f | ctr2 | pad][edges B*MAXE u32] ----
    char* w = (char*)d_ws;
    int* ecnt = (int*)w;                                  // im * 32 ints (128B apart)
    float* acc = (float*)(w + (size_t)B * 128);
    u32* ctr2 = (u32*)(w + (size_t)B * 128 + 8);
    size_t hdr = ((size_t)B * 128 + 12 + 127) & ~(size_t)127;
    u32* edges = (u32*)(w + hdr);

    hipMemsetAsync(d_ws, 0, hdr, stream);
    pair_kernel<<<dim3(B * NPAIR), dim3(256), 0, stream>>>(anchor_gt, props, ecnt, edges);
    scan_kernel<<<dim3(B), dim3(STH), 0, stream>>>(anchor_gt, gtb, props, ecnt, edges,
                                                   acc, ctr2, (float*)d_out, B);
}

// Round 15
// 48.331 us; speedup vs baseline: 8.4684x; 1.1365x over previous
//
#include <hip/hip_runtime.h>

#define NN 2048
#define GG 64
#define TS 128
#define NT (NN / TS)                 // 16 tiles
#define NPAIR (NT * (NT + 1) / 2)    // 136 tile pairs
#define MAXE 14336                   // per-image edge cap (est. E ~ 3000)
#define EBUF 3072                    // per-block LDS edge buffer
#define STH 1024                     // scan threads (16 waves)

typedef unsigned long long u64;
typedef unsigned short u16;
typedef unsigned int u32;

__device__ __forceinline__ float iou4(float4 a, float4 b) {
    float w = fminf(a.z, b.z) - fmaxf(a.x, b.x) + 1.0f;
    float h = fminf(a.w, b.w) - fmaxf(a.y, b.y) + 1.0f;
    w = fmaxf(w, 0.0f);
    h = fmaxf(h, 0.0f);
    float ov = w * h;
    float aa = (a.z - a.x + 1.0f) * (a.w - a.y + 1.0f);
    float ab = (b.z - b.x + 1.0f) * (b.w - b.y + 1.0f);
    return ov / (aa + ab - ov);
}

__device__ __forceinline__ float wredf(float v) {
    for (int o = 32; o > 0; o >>= 1) v += __shfl_down(v, o);
    return v;
}
__device__ __forceinline__ int wredi(int v) {
    for (int o = 32; o > 0; o >>= 1) v += __shfl_down(v, o);
    return v;
}
__device__ __forceinline__ u64 wredmin64(u64 v) {
    for (int o = 32; o > 0; o >>= 1) {
        u64 w = __shfl_down(v, o);
        v = (w < v) ? w : v;
    }
    return v;
}

// selection order: earlier = higher score, tie -> lower original index (scores >= 0).
__device__ __forceinline__ bool earlier(u32 sa, int a, u32 sb, int b) {
    return (sa > sb) || (sa == sb && a < b);
}
__device__ __forceinline__ u64 make_key(u32 sbits, int j) {
    return ((u64)sbits << 32) | (u64)(NN - 1 - j);
}

// ---------------- K0: zero header + pack proposals to SoA (replaces memset) ----------------
__global__ __launch_bounds__(256) void init_kernel(const int* __restrict__ gt_inds,
                                                   const float* __restrict__ props,
                                                   float4* __restrict__ sbox, float* __restrict__ ssc,
                                                   int* __restrict__ sgt,
                                                   int* __restrict__ ecnt, float* __restrict__ acc,
                                                   u32* __restrict__ ctr2) {
    __shared__ float pbL[NN * 5];        // 40 KB
    const int im = blockIdx.x, tid = threadIdx.x;
    if (tid < 32) ecnt[im * 32 + tid] = 0;
    if (im == 0 && tid == 0) { acc[0] = 0.f; acc[1] = 0.f; *ctr2 = 0u; }
    const float4* pv = (const float4*)(props + (size_t)im * NN * 5);
    float4* pl4 = (float4*)pbL;
    for (int x = tid; x < NN * 5 / 4; x += 256) pl4[x] = pv[x];   // linear, coalesced
    __syncthreads();
    const int base = im * NN;
    const int* gbi = gt_inds + (size_t)im * NN;
    for (int j = tid; j < NN; j += 256) {
        sbox[base + j] = make_float4(pbL[j * 5], pbL[j * 5 + 1], pbL[j * 5 + 2], pbL[j * 5 + 3]);
        ssc[base + j] = pbL[j * 5 + 4];
        sgt[base + j] = gbi[j];
    }
}

// ---------------- K1: balanced LDS-tiled pair phase -> compact edge list ----------------
__global__ __launch_bounds__(256) void pair_kernel(const float4* __restrict__ sbox,
                                                   const float* __restrict__ ssc,
                                                   const int* __restrict__ sgt,
                                                   int* __restrict__ ecnt, u32* __restrict__ edges) {
    const int im = blockIdx.x / NPAIR;
    int q = blockIdx.x % NPAIR;
    int ta = 0;
    while (q >= NT - ta) { q -= NT - ta; ++ta; }
    const int tb = ta + q;
    const int base = im * NN;

    __shared__ float4 Abox[TS], Bbox[TS];
    __shared__ u32 Asc[TS], Bsc[TS];
    __shared__ int Ag[TS], Bg[TS];
    __shared__ u32 ebuf[EBUF];
    __shared__ int lcnt, gbase;
    const int tid = threadIdx.x;
    if (tid == 0) lcnt = 0;

    for (int t = tid; t < TS; t += 256) {
        Abox[t] = sbox[base + ta * TS + t];
        Asc[t] = __float_as_uint(ssc[base + ta * TS + t]);
        Ag[t] = sgt[base + ta * TS + t];
        Bbox[t] = sbox[base + tb * TS + t];
        Bsc[t] = __float_as_uint(ssc[base + tb * TS + t]);
        Bg[t] = sgt[base + tb * TS + t];
    }
    __syncthreads();

    const int pr = tid & (TS - 1);      // row in tile A
    const int half = tid >> 7;          // column half in tile B
    const float4 rb = Abox[pr];
    const u32 rs = Asc[pr];
    const int i = ta * TS + pr;
    int* ec = ecnt + im * 32;           // 128B-padded per-image counter
    u32* ge = edges + (size_t)im * MAXE;
    if (Ag[pr] >= 0) {
        #pragma unroll 4
        for (int k = 0; k < TS / 2; ++k) {
            int jl = half * (TS / 2) + k;
            if (ta == tb && jl <= pr) continue;   // each unordered pair once
            if (Bg[jl] < 0) continue;
            float v = iou4(rb, Bbox[jl]);
            if (v > 0.5f) {
                int j = tb * TS + jl;
                int late, early;
                if (earlier(rs, i, Bsc[jl], j)) { late = j; early = i; }
                else                            { late = i; early = j; }
                u32 packed = ((u32)late << 16) | (u32)early;
                int slot = atomicAdd(&lcnt, 1);            // LDS atomic
                if (slot < EBUF) ebuf[slot] = packed;
                else {                                      // spill (essentially never)
                    int gs = atomicAdd(ec, 1);
                    if (gs < MAXE) ge[gs] = packed;
                }
            }
        }
    }
    __syncthreads();
    const int n = min(lcnt, EBUF);
    if (tid == 0) gbase = (n > 0) ? atomicAdd(ec, n) : 0;   // one global atomic per block
    __syncthreads();
    for (int e = tid; e < n; e += 256) {
        int gidx = gbase + e;
        if (gidx < MAXE) ge[gidx] = ebuf[e];                // coalesced copy
    }
}

// ---------------- K2: LDS CSR + worklist fixpoint + attribution + fused finalize ----------------
union SumWl {
    float sumA[NN];                   // 8 KB (pass 1/2 only)
    u16 wl[2][NN];                    // fixpoint worklists
};

__global__ __launch_bounds__(STH) void scan_kernel(const int* __restrict__ sgt,
                                                   const float* __restrict__ gt_boxes,
                                                   const float4* __restrict__ sbox,
                                                   const float* __restrict__ ssc,
                                                   const int* __restrict__ ecnt, const u32* __restrict__ edges,
                                                   float* __restrict__ acc, u32* __restrict__ ctr2,
                                                   float* __restrict__ out, int B) {
    __shared__ u32 scoreL[NN];            // 8 KB (float bits)
    __shared__ SumWl u;                   // 8 KB
    __shared__ int cw[NN];                // 8 KB: count -> cursor -> cntA
    __shared__ u16 eoff[NN + 2];          // 4.1 KB
    __shared__ u16 ent[MAXE];             // 28 KB
    __shared__ unsigned char st[NN];      // 0=unresolved 1=kept 2=killed
    __shared__ unsigned char hk[NN];
    __shared__ float4 gtb[GG];            // 1 KB
    __shared__ float4 recbox[GG];         // 1 KB (firstk boxes, staged after pass 1a)
    __shared__ u64 firstk[GG];            // max key among kept per gt (0 = none)
    __shared__ int wtot[STH / 64];
    __shared__ int s_cnt[2];              // parity worklist counters
    __shared__ u64 s_minkey;
    __shared__ int s_pos, s_qcnt, s_pcnt;
    __shared__ float s_tpush, s_tpull;

    const int im = blockIdx.x, tid = threadIdx.x;
    const int lane = tid & 63, wid = tid >> 6;
    const int base = im * NN;
    const u32* ge = edges + (size_t)im * MAXE;
    volatile unsigned char* vst = st;     // fixpoint reads must not be register-cached

    if (tid == 0) {
        s_pos = 0; s_qcnt = 0; s_pcnt = 0; s_tpush = 0.f; s_tpull = 0.f; s_minkey = ~0ull;
        s_cnt[0] = 0; s_cnt[1] = 0;
    }
    if (tid < GG) {
        firstk[tid] = 0ull;
        gtb[tid] = ((const float4*)(gt_boxes + (size_t)im * GG * 4))[tid];
    }
    int lpos = 0;
    for (int j = tid; j < NN; j += STH) {
        int g = sgt[base + j];
        st[j] = (g >= 0) ? 0 : 2;
        lpos += (g >= 0) ? 1 : 0;
        scoreL[j] = __float_as_uint(ssc[base + j]);
        cw[j] = 0; hk[j] = 0;
    }
    lpos = wredi(lpos);
    if (lane == 0 && lpos) atomicAdd(&s_pos, lpos);
    __syncthreads();

    // ---- build LDS CSR from the edge list ----
    const int E = min(ecnt[im * 32], MAXE);
    for (int e = tid; e < E; e += STH) atomicAdd(&cw[ge[e] >> 16], 1);
    __syncthreads();
    {   // block-wide exclusive prefix sum over 2048 counts (2 per thread, 16 waves)
        int j0 = tid * 2;
        int c0 = cw[j0], c1 = cw[j0 + 1];
        int s = c0 + c1;
        int incl = s;
        for (int o = 1; o < 64; o <<= 1) {
            int v = __shfl_up(incl, o);
            if (lane >= o) incl += v;
        }
        if (lane == 63) wtot[wid] = incl;
        __syncthreads();
        int wpre = 0;
        for (int wq = 0; wq < wid; ++wq) wpre += wtot[wq];
        int excl = wpre + incl - s;
        eoff[j0] = (u16)excl;
        eoff[j0 + 1] = (u16)(excl + c0);
        if (tid == STH - 1) eoff[NN] = (u16)(excl + s);
        cw[j0] = excl;
        cw[j0 + 1] = excl + c0;
    }
    __syncthreads();
    for (int e = tid; e < E; e += STH) {
        u32 x = ge[e];
        int pos = atomicAdd(&cw[x >> 16], 1);
        ent[pos] = (u16)(x & 0xffffu);
    }
    __syncthreads();

    // ---- fixpoint round 1: full sweep, compact unresolved into worklist 0 ----
    for (int j = tid; j < NN; j += STH) {
        if (st[j] != 0) continue;
        int e0 = eoff[j], e1 = eoff[j + 1];
        bool anyK = false, anyU = false;
        for (int e = e0; e < e1; ++e) {
            unsigned char s = vst[ent[e]];
            anyK |= (s == 1);
            anyU |= (s == 0);
        }
        if (anyK) st[j] = 2;
        else if (!anyU) st[j] = 1;
        else { int pos = atomicAdd(&s_cnt[0], 1); u.wl[0][pos] = (u16)j; }
    }
    __syncthreads();

    // ---- fixpoint rounds: worklist only, 3 relaxation sub-sweeps per barrier ----
    int src = 0;
    int nwl = s_cnt[0];
    while (nwl > 0) {
        #pragma unroll
        for (int r = 0; r < 2; ++r) {       // benign-race relaxations (monotone st)
            for (int w = tid; w < nwl; w += STH) {
                int j = u.wl[src][w];
                if (st[j] != 0) continue;
                int e0 = eoff[j], e1 = eoff[j + 1];
                bool anyK = false, anyU = false;
                for (int e = e0; e < e1; ++e) {
                    unsigned char s = vst[ent[e]];
                    anyK |= (s == 1);
                    anyU |= (s == 0);
                }
                if (anyK) st[j] = 2;
                else if (!anyU) st[j] = 1;
            }
        }
        for (int w = tid; w < nwl; w += STH) {
            int j = u.wl[src][w];
            if (st[j] != 0) continue;
            int e0 = eoff[j], e1 = eoff[j + 1];
            bool anyK = false, anyU = false;
            for (int e = e0; e < e1; ++e) {
                unsigned char s = vst[ent[e]];
                anyK |= (s == 1);
                anyU |= (s == 0);
            }
            if (anyK) st[j] = 2;
            else if (!anyU) st[j] = 1;
            else { int pos = atomicAdd(&s_cnt[src ^ 1], 1); u.wl[src ^ 1][pos] = (u16)j; }
        }
        __syncthreads();
        nwl = s_cnt[src ^ 1];
        if (tid == 0) s_cnt[src] = 0;
        src ^= 1;
        __syncthreads();
    }

    // ---- worklists dead; zero sumA and cw (cntA) ----
    for (int j = tid; j < NN; j += STH) { u.sumA[j] = 0.f; cw[j] = 0; }
    __syncthreads();

    // ---- pass 1a: kept bookkeeping — minkey via wave reduction ----
    u64 lmin = ~0ull;
    for (int j = tid; j < NN; j += STH) {
        if (st[j] != 1) continue;
        u64 kj = make_key(scoreL[j], j);
        if (kj < lmin) lmin = kj;
        atomicMax(&firstk[sgt[base + j]], kj);   // 64 distinct LDS addresses
    }
    lmin = wredmin64(lmin);
    if (lane == 0 && lmin != ~0ull) atomicMin(&s_minkey, lmin);   // 16 atomics total
    __syncthreads();

    // ---- stage firstk boxes into LDS (pass 2's pull partner) ----
    if (tid < GG) {
        u64 fk = firstk[tid];
        if (fk) recbox[tid] = sbox[base + (NN - 1) - (int)(fk & 0xffffffffu)];
    }

    // ---- pass 1b: killer attribution (killed positives only) ----
    for (int j = tid; j < NN; j += STH) {
        int g = sgt[base + j];
        if (st[j] != 2 || g < 0) continue;
        int e0 = eoff[j], e1 = eoff[j + 1];
        int ki = -1; u32 ks = 0;
        for (int e = e0; e < e1; ++e) {
            int ii = ent[e];
            if (st[ii] == 1 && (ki < 0 || earlier(scoreL[ii], ii, ks, ki))) { ki = ii; ks = scoreL[ii]; }
        }
        if (ki < 0) continue;             // cannot happen for a killed positive
        hk[ki] = 1;                       // benign race: all write 1
        float v = iou4(sbox[base + ki], sbox[base + j]);
        int gi = sgt[base + ki];
        if (g != gi && v > iou4(gtb[gi], gtb[g])) {
            atomicAdd(&cw[ki], 1);
            atomicAdd(&u.sumA[ki], -logf(1.5f - v) * __uint_as_float(scoreL[j]));
        }
    }
    __syncthreads();

    // ---- pass 2: accumulation over kept selections (order-free) ----
    float ltpush = 0.f, ltpull = 0.f;
    int lqcnt = 0, lpcnt = 0;
    const u64 minkey = s_minkey;
    for (int i = tid; i < NN; i += STH) {
        if (st[i] != 1) continue;
        int g = sgt[base + i];
        u64 ky = make_key(scoreL[i], i);
        u64 fk = firstk[g];
        bool add = (ky != minkey) || (hk[i] != 0);   // any(alive_p) at this selection
        int c = cw[i];
        bool hr = fk > ky;                            // earlier kept with same gt
        if (add && c > 0) ltpush += u.sumA[i] / (float)c;
        if (add) lqcnt += c;
        if (hr) ++lpcnt;                              // counted even when !add (matches ref)
        if (add && hr) {
            float v = iou4(sbox[base + i], recbox[g]);
            ltpull += -logf(fmaxf(v, 1e-6f)) * __uint_as_float(scoreL[i]);
        }
    }
    ltpush = wredf(ltpush); ltpull = wredf(ltpull);
    lqcnt = wredi(lqcnt); lpcnt = wredi(lpcnt);
    if (lane == 0) {
        if (ltpush != 0.f) atomicAdd(&s_tpush, ltpush);
        if (ltpull != 0.f) atomicAdd(&s_tpull, ltpull);
        if (lqcnt) atomicAdd(&s_qcnt, lqcnt);
        if (lpcnt) atomicAdd(&s_pcnt, lpcnt);
    }
    __syncthreads();

    // ---- cross-image finalize: last-finishing block writes the B-mean ----
    if (tid == 0) {
        float valid = (s_pos > 1) ? 1.0f : 0.0f;
        float push_b = s_tpush / ((float)s_qcnt + 1e-6f) * valid;
        float pull_b = s_tpull / ((float)s_pcnt + 1e-6f) * valid;
        atomicAdd(&acc[0], push_b);
        atomicAdd(&acc[1], pull_b);
        __threadfence();
        u32 old = atomicAdd(ctr2, 1u);
        if (old == (u32)(B - 1)) {
            float ps = atomicAdd(&acc[0], 0.0f);   // coherent device-scope read
            float pl = atomicAdd(&acc[1], 0.0f);
            float inv = 1.0f / (float)B;
            out[0] = ps * inv * 1.0f;  // push_loss * PUSH_W
            out[1] = pl * inv * 1.0f;  // pull_loss * PULL_W
        }
    }
}

extern "C" void kernel_launch(void* const* d_in, const int* in_sizes, int n_in,
                              void* d_out, int out_size, void* d_ws, size_t ws_size,
                              hipStream_t stream) {
    // inputs: 0=gt_inds(B*N i32), 1=anchor_gt_inds(B*N i32),
    //         2=gt_bboxes(B*G*4 f32), 3=proposal_list(B*N*5 f32)
    const int B = in_sizes[0] / NN;
    const int* anchor_gt = (const int*)d_in[1];
    const float* gtb = (const float*)d_in[2];
    const float* props = (const float*)d_in[3];

    // ---- workspace: [ecnt B*128B | acc | ctr2 | pad][sbox|ssc|sgt][edges] ----
    char* w = (char*)d_ws;
    int* ecnt = (int*)w;                                  // im * 32 ints (128B apart)
    float* acc = (float*)(w + (size_t)B * 128);
    u32* ctr2 = (u32*)(w + (size_t)B * 128 + 8);
    size_t o = (size_t)B * 128 + 128;
    float4* sbox = (float4*)(w + o);   o += (size_t)B * NN * 16;
    float* ssc = (float*)(w + o);      o += (size_t)B * NN * 4;
    int* sgt = (int*)(w + o);          o += (size_t)B * NN * 4;
    u32* edges = (u32*)(w + o);

    init_kernel<<<dim3(B), dim3(256), 0, stream>>>(anchor_gt, props, sbox, ssc, sgt, ecnt, acc, ctr2);
    pair_kernel<<<dim3(B * NPAIR), dim3(256), 0, stream>>>(sbox, ssc, sgt, ecnt, edges);
    scan_kernel<<<dim3(B), dim3(STH), 0, stream>>>(sgt, gtb, sbox, ssc, ecnt, edges,
                                                   acc, ctr2, (float*)d_out, B);
}